// Round 3
// baseline (287.923 us; speedup 1.0000x reference)
//
#include <hip/hip_runtime.h>

// BioNorm: out = w * x^p / (sigma^p + depthwise_conv5x5(x^p, edge-pad)) + b
// B=32, C=64, H=W=112, K=5, fp32.
//
// R3: vertical sliding window. R2 spilled (VGPR=48 vs ~70 live -> scratch,
// latency-bound at 18% VALU / 21% HBM). Now: lane = column (stride-1 LDS
// access = conflict-free), thread slides a 5x5 register window down 28 rows.
// Per output row: 5 ds_read_b32 taps + 25 FMA. Circular %5 window with
// template-constant trip counts -> all register indices compile-time.
//
// Edge semantics: replicate-pad of the VALID-conv result == window centered
// at (clamp(r,2,109), clamp(w,2,109)). We iterate over distinct clamped row
// centers cc (window always advances); rows 0,1 (resp 110,111) are
// extra-emitted from the cc=2 (cc=109) window, numerators read from LDS.
// Edge columns 0,1,110,111: numerator x^p(cc,col) is already a window tap
// (window at cw=2 spans cols 0..4) -> 4-way cndmask select, no extra LDS.

#define Cch 64
#define Hh 112
#define Ww 112
#define TH 56            // output rows per block (112 = 2*56)
#define LROWS (TH + 4)   // 60 staged rows
#define STR 112          // LDS row stride in floats (lane stride 1 -> no conflicts)

template<int NITER, bool TOP, bool BOT>
__device__ __forceinline__ void run_strip(
    const float* lds, const float kw[25],
    int r0, int rstart, int col, float sp, float wc, float bc,
    float* __restrict__ oplane)
{
    const int cw   = col < 2 ? 2 : (col > 109 ? 109 : col);
    const int base = cw - 2;                 // window column base (lane-varying)
    const int cidx = col - base;             // 0,1 | 2 | 3,4 : numerator tap index
    const int cc0  = TOP ? 2 : rstart;       // first clamped row center
    const bool store_ok = col < Ww;
    const int lcol = col < Ww ? col : (Ww - 1);   // safe LDS col for idle lanes

    float win[5][5];                         // win[(i+dy)%5][dx] = logical row dy
    #pragma unroll
    for (int dy = 0; dy < 5; ++dy) {
        const int s = cc0 - r0 + dy;         // LDS row of global row cc0-2+dy
        #pragma unroll
        for (int dx = 0; dx < 5; ++dx)
            win[dy][dx] = lds[s * STR + base + dx];
    }

    #pragma unroll
    for (int i = 0; i < NITER; ++i) {
        if (i > 0) {
            const int s  = cc0 + i + 4 - r0; // LDS row of new bottom row cc0+i+2
            const int ph = (i + 4) % 5;
            #pragma unroll
            for (int dx = 0; dx < 5; ++dx)
                win[ph][dx] = lds[s * STR + base + dx];
        }
        float sum = 0.f;
        #pragma unroll
        for (int dy = 0; dy < 5; ++dy)
            #pragma unroll
            for (int dx = 0; dx < 5; ++dx)
                sum = fmaf(kw[dy * 5 + dx], win[(i + dy) % 5][dx], sum);

        const float* wrow = win[(i + 2) % 5];
        float num = wrow[2];                 // x^p(cc, col) for interior cols
        if (cidx == 0) num = wrow[0];
        else if (cidx == 1) num = wrow[1];
        else if (cidx == 3) num = wrow[3];
        else if (cidx == 4) num = wrow[4];

        const int   cc   = cc0 + i;
        const float invd = __builtin_amdgcn_rcpf(sp + sum);
        if (store_ok) oplane[cc * Ww + col] = fmaf(wc * num, invd, bc);

        if (TOP && i == 0) {                 // rows 0,1 share the cc=2 window sum
            #pragma unroll
            for (int r = 0; r < 2; ++r) {
                const float n2 = lds[(r + 2) * STR + lcol];       // r0==0
                if (store_ok) oplane[r * Ww + col] = fmaf(wc * n2, invd, bc);
            }
        }
        if (BOT && i == NITER - 1) {         // rows 110,111 share the cc=109 sum
            #pragma unroll
            for (int r = 110; r < 112; ++r) {
                const float n2 = lds[(r - r0 + 2) * STR + lcol];
                if (store_ok) oplane[r * Ww + col] = fmaf(wc * n2, invd, bc);
            }
        }
    }
}

__global__ __launch_bounds__(256) void bionorm_kernel(
    const float* __restrict__ x, const float* __restrict__ sigma,
    const float* __restrict__ pow_p, const float* __restrict__ sum_kernel,
    const float* __restrict__ weight, const float* __restrict__ bias,
    float* __restrict__ out)
{
    __shared__ float lds[LROWS * STR];

    const int rt  = blockIdx.x;   // 0..1
    const int c   = blockIdx.y;
    const int b   = blockIdx.z;
    const int tid = threadIdx.x;
    const int r0  = rt * TH;

    const float p  = pow_p[c];
    const float sg = sigma[c];
    const float wc = weight[c];
    const float bc = bias[c];
    const bool  p2 = (p == 2.0f);
    const float sp = p2 ? sg * sg : __powf(sg, p);

    float kw[25];
    const float* kp = sum_kernel + c * 25;
    #pragma unroll
    for (int j = 0; j < 25; ++j) kw[j] = kp[j];   // uniform -> SGPRs

    const float* xplane = x + ((size_t)(b * Cch + c)) * Hh * Ww;

    // ---- stage x^p: 60 rows x 112 cols, float4 ----
    for (int i = tid; i < LROWS * 28; i += 256) {
        int s = i / 28, q = i - s * 28;
        int g = r0 - 2 + s;
        g = g < 0 ? 0 : (g > 111 ? 111 : g);
        const float4 v = *(const float4*)(xplane + g * Ww + q * 4);
        float4 xp;
        if (p2) {
            xp.x = v.x * v.x; xp.y = v.y * v.y;
            xp.z = v.z * v.z; xp.w = v.w * v.w;
        } else {
            xp.x = __powf(v.x, p); xp.y = __powf(v.y, p);
            xp.z = __powf(v.z, p); xp.w = __powf(v.w, p);
        }
        *(float4*)(&lds[s * STR + q * 4]) = xp;
    }
    __syncthreads();

    const int col    = tid & 127;          // lane -> column (112 active)
    const int grp    = tid >> 7;           // 2 row groups of 28
    const int rstart = r0 + grp * 28;
    float* oplane = out + ((size_t)(b * Cch + c)) * Hh * Ww;

    if (rstart == 0)
        run_strip<26, true,  false>(lds, kw, r0, rstart, col, sp, wc, bc, oplane);
    else if (rstart == 84)
        run_strip<26, false, true >(lds, kw, r0, rstart, col, sp, wc, bc, oplane);
    else
        run_strip<28, false, false>(lds, kw, r0, rstart, col, sp, wc, bc, oplane);
}

extern "C" void kernel_launch(void* const* d_in, const int* in_sizes, int n_in,
                              void* d_out, int out_size, void* d_ws, size_t ws_size,
                              hipStream_t stream) {
    const float* x          = (const float*)d_in[0];
    const float* sigma      = (const float*)d_in[1];
    const float* pow_p      = (const float*)d_in[2];
    const float* sum_kernel = (const float*)d_in[3];
    const float* weight     = (const float*)d_in[4];
    const float* bias       = (const float*)d_in[5];
    float* out = (float*)d_out;

    dim3 grid(2, Cch, 32);   // (row tiles, C, B)
    dim3 block(256);
    bionorm_kernel<<<grid, block, 0, stream>>>(x, sigma, pow_p, sum_kernel,
                                               weight, bias, out);
}